// Round 12
// baseline (770.549 us; speedup 1.0000x reference)
//
#include <hip/hip_runtime.h>
#include <math.h>

#define N_NODES 20000
#define N_PAD   20096            // 157 * 128
#define N_EDGES 100000
#define N_GRAPHS 64
#define IN_F 63
#define NHEAD 8
#define F 1024                   // NHEAD * HID
#define NCLS 18
#define BN_EPS 1e-5f
#define BN_CHUNKS 256

typedef __attribute__((ext_vector_type(8))) _Float16 half8v;  // 8 f16 (4 VGPRs)
typedef __attribute__((ext_vector_type(4))) _Float16 half4v;
typedef __attribute__((ext_vector_type(4))) float f32x4;

// ---------------- CSR build over dst ----------------
__global__ void k_count(const int* __restrict__ dst, int* __restrict__ cnt) {
    int i = blockIdx.x * blockDim.x + threadIdx.x;
    if (i < N_EDGES) atomicAdd(&cnt[dst[i]], 1);
}

// exclusive scan over cnt -> off (1024 threads); also per-graph starts (gstart)
__global__ void k_scan(const int* __restrict__ cnt, int* __restrict__ off,
                       const int* __restrict__ gid, int* __restrict__ gstart) {
    __shared__ int tsum[1024];
    const int CH = (N_NODES + 1023) / 1024;   // 20
    int t = threadIdx.x;
    int s = 0;
    for (int i = 0; i < CH; ++i) {
        int idx = t * CH + i;
        if (idx < N_NODES) s += cnt[idx];
    }
    tsum[t] = s;
    __syncthreads();
    if (t == 0) {
        int acc = 0;
        for (int i = 0; i < 1024; ++i) { int v = tsum[i]; tsum[i] = acc; acc += v; }
    }
    __syncthreads();
    int run = tsum[t];
    for (int i = 0; i < CH; ++i) {
        int idx = t * CH + i;
        if (idx < N_NODES) { off[idx] = run; run += cnt[idx]; }
    }
    if (t == 1023) off[N_NODES] = run;
    if (t <= N_GRAPHS) {
        int lo = 0, hi = N_NODES;
        while (lo < hi) {
            int mid = (lo + hi) >> 1;
            if (gid[mid] < t) lo = mid + 1; else hi = mid;
        }
        gstart[t] = lo;
    }
}

// fill CSR using a second zeroed counter (fcnt); deterministic after sort
__global__ void k_fill(const int* __restrict__ dst, const int* __restrict__ off,
                       int* __restrict__ fcnt, int* __restrict__ csr_e) {
    int i = blockIdx.x * blockDim.x + threadIdx.x;
    if (i < N_EDGES) {
        int d = dst[i];
        int p = atomicAdd(&fcnt[d], 1);
        csr_e[off[d] + p] = i;
    }
}

__global__ void k_sort_buckets(const int* __restrict__ off, int* __restrict__ csr_e) {
    int n = blockIdx.x * blockDim.x + threadIdx.x;
    if (n >= N_NODES) return;
    int b = off[n], e = off[n + 1];
    for (int i = b + 1; i < e; ++i) {
        int v = csr_e[i];
        int j = i - 1;
        while (j >= b && csr_e[j] > v) { csr_e[j + 1] = csr_e[j]; --j; }
        csr_e[j + 1] = v;
    }
}

// ---------------- input prep: h->f16 [N_PAD][64] + zero stride-F pad rows ----------
__global__ void k_prep(const float* __restrict__ h, _Float16* __restrict__ xh) {
    const int T1 = N_PAD * 64;
    const int T2 = (N_PAD - N_NODES) * F;
    int idx = blockIdx.x * 256 + threadIdx.x;
    if (idx < T1) {
        int m = idx >> 6, k = idx & 63;
        float v = (m < N_NODES && k < IN_F) ? h[m * IN_F + k] : 0.f;
        xh[idx] = (_Float16)v;
    } else if (idx < T1 + T2) {
        xh[(size_t)N_NODES * F + (idx - T1)] = (_Float16)0.f;
    }
}

// W [K][1024] f32 -> W^T [1024][Kpad] f16; two matrices per launch (grid.z)
__global__ void k_cvt_w2(const float* __restrict__ W0, _Float16* __restrict__ o0,
                         const float* __restrict__ W1, _Float16* __restrict__ o1,
                         int K, int Kpad) {
    const float* W = blockIdx.z ? W1 : W0;
    _Float16* wh = blockIdx.z ? o1 : o0;
    __shared__ float t[32][33];
    int kt = blockIdx.x * 32, nt = blockIdx.y * 32;
    int tx = threadIdx.x & 31, ty = threadIdx.x >> 5;
#pragma unroll
    for (int j = 0; j < 4; ++j) {
        int k = kt + ty + j * 8;
        t[ty + j * 8][tx] = (k < K) ? W[(size_t)k * F + nt + tx] : 0.f;
    }
    __syncthreads();
#pragma unroll
    for (int j = 0; j < 4; ++j) {
        int n = nt + ty + j * 8;
        wh[(size_t)n * Kpad + kt + tx] = (_Float16)t[tx][ty + j * 8];
    }
}

// six K=1024 weight matrices in one launch (grid.z = 6)
__global__ void k_cvt_w6(const float* __restrict__ a0, _Float16* __restrict__ b0,
                         const float* __restrict__ a1, _Float16* __restrict__ b1,
                         const float* __restrict__ a2, _Float16* __restrict__ b2,
                         const float* __restrict__ a3, _Float16* __restrict__ b3,
                         const float* __restrict__ a4, _Float16* __restrict__ b4,
                         const float* __restrict__ a5, _Float16* __restrict__ b5) {
    const float* W; _Float16* wh;
    switch (blockIdx.z) {
        case 0: W = a0; wh = b0; break;
        case 1: W = a1; wh = b1; break;
        case 2: W = a2; wh = b2; break;
        case 3: W = a3; wh = b3; break;
        case 4: W = a4; wh = b4; break;
        default: W = a5; wh = b5; break;
    }
    __shared__ float t[32][33];
    int kt = blockIdx.x * 32, nt = blockIdx.y * 32;
    int tx = threadIdx.x & 31, ty = threadIdx.x >> 5;
#pragma unroll
    for (int j = 0; j < 4; ++j) {
        int k = kt + ty + j * 8;
        t[ty + j * 8][tx] = W[(size_t)k * F + nt + tx];
    }
    __syncthreads();
#pragma unroll
    for (int j = 0; j < 4; ++j) {
        int n = nt + ty + j * 8;
        wh[(size_t)n * F + kt + tx] = (_Float16)t[tx][ty + j * 8];
    }
}

// ---------------- fused dual f16 MFMA GEMM, BK=64, XOR-swizzled LDS (r6 exact) ----
#define AS1C(p) ((const __attribute__((address_space(1))) void*)(p))
#define AS3(p)  ((__attribute__((address_space(3))) void*)(p))

__launch_bounds__(256, 2)
__global__ void k_gemm_dual(const _Float16* __restrict__ A,
                            const _Float16* __restrict__ Bs, const _Float16* __restrict__ Bd,
                            const float* __restrict__ bias_s, const float* __restrict__ bias_d,
                            _Float16* __restrict__ Cs, _Float16* __restrict__ Cd, int Kpad) {
    __shared__ _Float16 lds[24576];   // 3 tiles x [128][64] f16 = 48 KiB
    const int tid = threadIdx.x;
    const int l = tid & 63, w = tid >> 6;

    // XCD-aware bijective swizzle: nwg = 8*157 = 1256, 1256 % 8 == 0
    const int orig = blockIdx.y * 8 + blockIdx.x;
    const int wg = (orig & 7) * (N_PAD / 128) + (orig >> 3);
    const int by = wg >> 3, bx = wg & 7;

    const int grow = w * 32 + (l >> 3);
    const int gcol = ((l & 7) ^ (l >> 3)) << 3;         // swizzled 16B chunk (halves)
    const size_t rstep = (size_t)8 * Kpad;
    const _Float16* gA = A + (size_t)(by * 128 + grow) * Kpad + gcol;
    const _Float16* gBs = Bs + (size_t)(bx * 128 + grow) * Kpad + gcol;
    const _Float16* gBd = Bd + (size_t)(bx * 128 + grow) * Kpad + gcol;
    char* sA = (char*)lds + w * 4096;
    char* sBs = (char*)lds + 16384 + w * 4096;
    char* sBd = (char*)lds + 32768 + w * 4096;

    const int wr = (w >> 1) * 64, wc = (w & 1) * 64;
    const int frow = l & 15;
    const int swz = (l & 7) << 4;                       // read-side XOR (row&7 == l&7)
    const int kbase = (l >> 4) * 16;

    f32x4 accS[4][4], accD[4][4];
    const f32x4 fzero = {0.f, 0.f, 0.f, 0.f};
#pragma unroll
    for (int i = 0; i < 4; ++i)
#pragma unroll
        for (int j = 0; j < 4; ++j) { accS[i][j] = fzero; accD[i][j] = fzero; }

    for (int k0 = 0; k0 < Kpad; k0 += 64) {
#pragma unroll
        for (int j = 0; j < 4; ++j) {
            __builtin_amdgcn_global_load_lds(AS1C(gA + j * rstep), AS3(sA + j * 1024), 16, 0, 0);
            __builtin_amdgcn_global_load_lds(AS1C(gBs + j * rstep), AS3(sBs + j * 1024), 16, 0, 0);
            __builtin_amdgcn_global_load_lds(AS1C(gBd + j * rstep), AS3(sBd + j * 1024), 16, 0, 0);
        }
        gA += 64; gBs += 64; gBd += 64;
        __syncthreads();

#pragma unroll
        for (int kk = 0; kk < 2; ++kk) {
            const int kb = (kk * 64 + kbase) ^ swz;
            half8v a[4];
#pragma unroll
            for (int mi = 0; mi < 4; ++mi) {
                int row = wr + mi * 16 + frow;
                a[mi] = *(const half8v*)((const char*)lds + row * 128 + kb);
            }
#pragma unroll
            for (int ni = 0; ni < 4; ++ni) {
                int rowb = wc + ni * 16 + frow;
                half8v bs = *(const half8v*)((const char*)lds + 16384 + rowb * 128 + kb);
                half8v bd = *(const half8v*)((const char*)lds + 32768 + rowb * 128 + kb);
#pragma unroll
                for (int mi = 0; mi < 4; ++mi) {
                    accS[mi][ni] = __builtin_amdgcn_mfma_f32_16x16x32_f16(a[mi], bs, accS[mi][ni], 0, 0, 0);
                    accD[mi][ni] = __builtin_amdgcn_mfma_f32_16x16x32_f16(a[mi], bd, accD[mi][ni], 0, 0, 0);
                }
            }
        }
        __syncthreads();
    }

    // epilogue: C/D layout col = lane&15, row = (lane>>4)*4 + reg; f16 stores
    const int crow0 = by * 128 + wr + (l >> 4) * 4;
    const int ccol = bx * 128 + wc + (l & 15);
    float bS[4], bD[4];
#pragma unroll
    for (int ni = 0; ni < 4; ++ni) { bS[ni] = bias_s[ccol + ni * 16]; bD[ni] = bias_d[ccol + ni * 16]; }
#pragma unroll
    for (int mi = 0; mi < 4; ++mi) {
#pragma unroll
        for (int r = 0; r < 4; ++r) {
            int row = crow0 + mi * 16 + r;
            if (row < N_NODES) {
#pragma unroll
                for (int ni = 0; ni < 4; ++ni) {
                    int col = ccol + ni * 16;
                    Cs[(size_t)row * F + col] = (_Float16)(accS[mi][ni][r] + bS[ni]);
                    Cd[(size_t)row * F + col] = (_Float16)(accD[mi][ni][r] + bD[ni]);
                }
            }
        }
    }
}

// ---------------- fused GATv2 edge+softmax+aggregate (online softmax, f16 io) ----
// 128 threads/block, one block per dst node; 8 f16 per thread (16B/lane).
// 1-deep prefetch: fs[s_src[i+1]] load issued before edge-i compute (T14).
__launch_bounds__(128)
__global__ void k_gat(const _Float16* __restrict__ fs, const _Float16* __restrict__ fd,
                      const int* __restrict__ off, const int* __restrict__ csr_e,
                      const int* __restrict__ src, const float* __restrict__ attn,
                      const float* __restrict__ bias, _Float16* __restrict__ y16) {
    __shared__ int s_src[128];
    const int n = blockIdx.x;
    const int t = threadIdx.x;
    const int b = off[n], e = off[n + 1];

    half8v fdv8 = *(const half8v*)(fd + (size_t)n * F + t * 8);
    float fdv[8], av[8];
    const float4 a0 = *(const float4*)(attn + (t >> 4) * 128 + (t & 15) * 8);
    const float4 a1 = *(const float4*)(attn + (t >> 4) * 128 + (t & 15) * 8 + 4);
    av[0] = a0.x; av[1] = a0.y; av[2] = a0.z; av[3] = a0.w;
    av[4] = a1.x; av[5] = a1.y; av[6] = a1.z; av[7] = a1.w;
#pragma unroll
    for (int j = 0; j < 8; ++j) fdv[j] = (float)fdv8[j];

    float m = -1e30f, den = 0.f;
    float acc[8] = {0.f, 0.f, 0.f, 0.f, 0.f, 0.f, 0.f, 0.f};

    for (int c0 = b; c0 < e; c0 += 128) {
        int ncur = e - c0; if (ncur > 128) ncur = 128;
        __syncthreads();
        if (t < ncur) s_src[t] = src[csr_e[c0 + t]];
        __syncthreads();
        half8v nxt = *(const half8v*)(fs + (size_t)s_src[0] * F + t * 8);
        for (int i = 0; i < ncur; ++i) {
            half8v cur = nxt;
            if (i + 1 < ncur)
                nxt = *(const half8v*)(fs + (size_t)s_src[i + 1] * F + t * 8);
            float f[8];
            float p = 0.f;
#pragma unroll
            for (int j = 0; j < 8; ++j) {
                f[j] = (float)cur[j];
                float v = f[j] + fdv[j];
                v = v > 0.f ? v : 0.2f * v;
                p += v * av[j];
            }
            p += __shfl_xor(p, 1);
            p += __shfl_xor(p, 2);
            p += __shfl_xor(p, 4);
            p += __shfl_xor(p, 8);     // 16-lane head group holds full score
            float mn = fmaxf(m, p);
            float so = __expf(m - mn);
            float wexp = __expf(p - mn);
            den = den * so + wexp;
#pragma unroll
            for (int j = 0; j < 8; ++j) acc[j] = acc[j] * so + wexp * f[j];
            m = mn;
        }
    }
    float inv = (e > b) ? 1.f / den : 0.f;
    const float4 b0 = *(const float4*)(bias + t * 8);
    const float4 b1 = *(const float4*)(bias + t * 8 + 4);
    float bb[8] = {b0.x, b0.y, b0.z, b0.w, b1.x, b1.y, b1.z, b1.w};
    half8v o;
#pragma unroll
    for (int j = 0; j < 8; ++j) o[j] = (_Float16)(acc[j] * inv + bb[j]);
    *(half8v*)(y16 + (size_t)n * F + t * 8) = o;
}

// ---------------- BatchNorm (2-stage deterministic) + lrelu, f16 io ----------------
// half8v reads: thread t covers cols (t&127)*8..+8, rows r0+(t>>7) stepping 2.
// part layout: [BN_CHUNKS*2][2*F] (sub-partials summed in k_bnfin, fixed order).
__global__ void k_bnpart(const _Float16* __restrict__ y16, float* __restrict__ part) {
    const int ROWS = (N_NODES + BN_CHUNKS - 1) / BN_CHUNKS;   // 79
    int blk = blockIdx.x;
    int t = threadIdx.x;
    int sub = t >> 7;
    int c8 = (t & 127) * 8;
    int r0 = blk * ROWS + sub;
    int r1 = blk * ROWS + ROWS; if (r1 > N_NODES) r1 = N_NODES;
    float s[8] = {}, q[8] = {};
    for (int r = r0; r < r1; r += 2) {
        half8v v = *(const half8v*)(y16 + (size_t)r * F + c8);
#pragma unroll
        for (int j = 0; j < 8; ++j) {
            float f = (float)v[j];
            s[j] += f; q[j] += f * f;
        }
    }
    float* ps = part + (size_t)(blk * 2 + sub) * (2 * F);
#pragma unroll
    for (int j = 0; j < 8; ++j) {
        ps[c8 + j] = s[j];
        ps[F + c8 + j] = q[j];
    }
}

__global__ void k_bnfin(const float* __restrict__ part, const float* __restrict__ gamma,
                        const float* __restrict__ beta, float* __restrict__ scale,
                        float* __restrict__ shift) {
    int c = blockIdx.x * blockDim.x + threadIdx.x;
    if (c >= F) return;
    float s = 0.f, q = 0.f;
    for (int b = 0; b < BN_CHUNKS * 2; ++b) {
        s += part[(size_t)b * (2 * F) + c];
        q += part[(size_t)b * (2 * F) + F + c];
    }
    float mu = s / (float)N_NODES;
    float var = q / (float)N_NODES - mu * mu;
    float sc = gamma[c] * rsqrtf(var + BN_EPS);
    scale[c] = sc;
    shift[c] = beta[c] - mu * sc;
}

// BN+lrelu from f16 y -> f16 xh; half8v (16B/lane) both sides
__global__ void k_bnapply(const _Float16* __restrict__ y16, const float* __restrict__ scale,
                          const float* __restrict__ shift, _Float16* __restrict__ xh) {
    int i = blockIdx.x * blockDim.x + threadIdx.x;
    if (i >= N_NODES * (F / 8)) return;
    int c8 = (i & (F / 8 - 1)) * 8;
    half8v v = ((const half8v*)y16)[i];
    half8v h8;
#pragma unroll
    for (int j = 0; j < 8; ++j) {
        float o = (float)v[j] * scale[c8 + j] + shift[c8 + j];
        o = o > 0.f ? o : 0.01f * o;
        h8[j] = (_Float16)o;
    }
    ((half8v*)xh)[i] = h8;
}

// ---------------- layer-3 fused BN+lrelu+avg-pool (y16 -> hg16) ----------------
__global__ void k_pool_bn(const _Float16* __restrict__ y16, const float* __restrict__ scale,
                          const float* __restrict__ shift, const int* __restrict__ gstart,
                          _Float16* __restrict__ hg16) {
    int g = blockIdx.y;
    int col = blockIdx.x * 256 + threadIdx.x;
    float sc = scale[col], sh = shift[col];
    int r0 = gstart[g], r1 = gstart[g + 1];
    float s = 0.f;
    for (int r = r0; r < r1; ++r) {
        float v = (float)y16[(size_t)r * F + col] * sc + sh;
        s += v > 0.f ? v : 0.01f * v;
    }
    float inv = (r1 > r0) ? 1.f / (float)(r1 - r0) : 0.f;
    hg16[(size_t)g * F + col] = (_Float16)(s * inv);
}

// ---------------- MLP fc1/fc2: f16 MFMA GEMM, M=64, N=K=1024 ----------------
__launch_bounds__(256)
__global__ void k_mlp_mfma(const _Float16* __restrict__ A16, const _Float16* __restrict__ Bt,
                           const float* __restrict__ bias, _Float16* __restrict__ out16,
                           float* __restrict__ out32, int mode) {
    const int l = threadIdx.x & 63, w = threadIdx.x >> 6;
    const int bx = blockIdx.x;
    const int fko = (l >> 4) * 8;

    const _Float16* pa = A16 + (size_t)(w * 16 + (l & 15)) * 1024 + fko;
    const _Float16* pb = Bt + (size_t)(bx * 64 + (l & 15)) * 1024 + fko;

    f32x4 acc[4];
    const f32x4 fzero = {0.f, 0.f, 0.f, 0.f};
#pragma unroll
    for (int ni = 0; ni < 4; ++ni) acc[ni] = fzero;

#pragma unroll 4
    for (int k0 = 0; k0 < 1024; k0 += 32) {
        half8v a = *(const half8v*)(pa + k0);
#pragma unroll
        for (int ni = 0; ni < 4; ++ni) {
            half8v b = *(const half8v*)(pb + (size_t)ni * 16 * 1024 + k0);
            acc[ni] = __builtin_amdgcn_mfma_f32_16x16x32_f16(a, b, acc[ni], 0, 0, 0);
        }
    }

    const int row0 = w * 16 + (l >> 4) * 4;
    const int col0 = bx * 64 + (l & 15);
#pragma unroll
    for (int ni = 0; ni < 4; ++ni) {
        int col = col0 + ni * 16;
        float bb = bias[col];
#pragma unroll
        for (int r = 0; r < 4; ++r) {
            float v = acc[ni][r] + bb;
            v = v > 0.f ? v : 0.01f * v;
            if (mode == 0) out16[(size_t)(row0 + r) * 1024 + col] = (_Float16)v;
            else out32[(size_t)(row0 + r) * 1024 + col] = v;
        }
    }
}

// ---------------- fc3: one wave per output, f32 shfl reduction ----------------
__global__ void k_fc3(const float* __restrict__ z2, const float* __restrict__ W,
                      const float* __restrict__ b, float* __restrict__ out) {
    int gw = (blockIdx.x * blockDim.x + threadIdx.x) >> 6;
    int lane = threadIdx.x & 63;
    if (gw >= N_GRAPHS * NCLS) return;
    int row = gw / NCLS, col = gw - row * NCLS;
    float s = 0.f;
    for (int k = lane; k < 1024; k += 64) s += z2[(size_t)row * 1024 + k] * W[(size_t)k * NCLS + col];
#pragma unroll
    for (int o = 32; o; o >>= 1) s += __shfl_down(s, o);
    if (lane == 0) out[(size_t)row * NCLS + col] = s + b[col];
}

// ---------------- host orchestration ----------------
extern "C" void kernel_launch(void* const* d_in, const int* in_sizes, int n_in,
                              void* d_out, int out_size, void* d_ws, size_t ws_size,
                              hipStream_t stream) {
    const float* h = (const float*)d_in[0];
    const int* src = (const int*)d_in[1];
    const int* dst = (const int*)d_in[2];
    const int* gid = (const int*)d_in[3];

    const float *w_src[3], *b_src[3], *w_dst[3], *b_dst[3], *attn[3], *bias[3], *gamma[3], *beta[3];
    for (int l = 0; l < 3; ++l) {
        int base = 4 + l * 8;
        w_src[l] = (const float*)d_in[base + 0];
        b_src[l] = (const float*)d_in[base + 1];
        w_dst[l] = (const float*)d_in[base + 2];
        b_dst[l] = (const float*)d_in[base + 3];
        attn[l]  = (const float*)d_in[base + 4];
        bias[l]  = (const float*)d_in[base + 5];
        gamma[l] = (const float*)d_in[base + 6];
        beta[l]  = (const float*)d_in[base + 7];
    }
    const float* fc1_w = (const float*)d_in[28];
    const float* fc1_b = (const float*)d_in[29];
    const float* fc2_w = (const float*)d_in[30];
    const float* fc2_b = (const float*)d_in[31];
    const float* fc3_w = (const float*)d_in[32];
    const float* fc3_b = (const float*)d_in[33];

    // workspace carve
    char* base = (char*)d_ws;
    size_t o = 0;
    auto carve = [&](size_t bytes) -> char* {
        char* p = base + o;
        o += (bytes + 255) & ~(size_t)255;
        return p;
    };
    _Float16* fs16 = (_Float16*)carve((size_t)N_NODES * F * 2);
    _Float16* fd16 = (_Float16*)carve((size_t)N_NODES * F * 2);
    _Float16* y16 = (_Float16*)carve((size_t)N_NODES * F * 2);
    _Float16* xh = (_Float16*)carve((size_t)N_PAD * F * 2);
    _Float16* w1s = (_Float16*)carve((size_t)F * 64 * 2);
    _Float16* w1d = (_Float16*)carve((size_t)F * 64 * 2);
    _Float16* w2s = (_Float16*)carve((size_t)F * F * 2);
    _Float16* w2d = (_Float16*)carve((size_t)F * F * 2);
    _Float16* w3s = (_Float16*)carve((size_t)F * F * 2);
    _Float16* w3d = (_Float16*)carve((size_t)F * F * 2);
    _Float16* fc1h = (_Float16*)carve((size_t)F * F * 2);
    _Float16* fc2h = (_Float16*)carve((size_t)F * F * 2);
    int* cnt = (int*)carve((size_t)2 * N_NODES * 4);      // [cnt | fill-cursor]
    int* fcnt = cnt + N_NODES;
    int* off = (int*)carve((size_t)(N_NODES + 1) * 4);
    int* csr_e = (int*)carve((size_t)N_EDGES * 4);
    float* part = (float*)carve((size_t)BN_CHUNKS * 2 * 2 * F * 4);
    float* scale = (float*)carve(F * 4);
    float* shift = (float*)carve(F * 4);
    int* gstart = (int*)carve((N_GRAPHS + 1) * 4);
    _Float16* hg16 = (_Float16*)carve((size_t)N_GRAPHS * F * 2);
    _Float16* z1h = (_Float16*)carve((size_t)N_GRAPHS * F * 2);
    float* z2 = (float*)carve((size_t)N_GRAPHS * F * 4);
    (void)ws_size;

    // ---- CSR build (deterministic: buckets sorted by edge id) ----
    hipMemsetAsync(cnt, 0, (size_t)2 * N_NODES * 4, stream);
    k_count<<<(N_EDGES + 255) / 256, 256, 0, stream>>>(dst, cnt);
    k_scan<<<1, 1024, 0, stream>>>(cnt, off, gid, gstart);
    k_fill<<<(N_EDGES + 255) / 256, 256, 0, stream>>>(dst, off, fcnt, csr_e);
    k_sort_buckets<<<(N_NODES + 255) / 256, 256, 0, stream>>>(off, csr_e);

    // ---- input conversion + all weight conversions up-front ----
    const int PREP_T = N_PAD * 64 + (N_PAD - N_NODES) * F;
    k_prep<<<(PREP_T + 255) / 256, 256, 0, stream>>>(h, xh);
    k_cvt_w2<<<dim3(2, F / 32, 2), 256, 0, stream>>>(w_src[0], w1s, w_dst[0], w1d, IN_F, 64);
    k_cvt_w6<<<dim3(F / 32, F / 32, 6), 256, 0, stream>>>(
        w_src[1], w2s, w_dst[1], w2d, w_src[2], w3s, w_dst[2], w3d, fc1_w, fc1h, fc2_w, fc2h);

    // ---- 3 GATv2 + BN + lrelu layers ----
    const dim3 ggrid(8, N_PAD / 128);
    const _Float16* ws16[3] = {w1s, w2s, w3s};
    const _Float16* wd16[3] = {w1d, w2d, w3d};
    for (int l = 0; l < 3; ++l) {
        const int Kp = (l == 0) ? 64 : F;
        k_gemm_dual<<<ggrid, 256, 0, stream>>>(xh, ws16[l], wd16[l], b_src[l], b_dst[l],
                                               fs16, fd16, Kp);
        k_gat<<<N_NODES, 128, 0, stream>>>(fs16, fd16, off, csr_e, src, attn[l], bias[l], y16);
        k_bnpart<<<BN_CHUNKS, 256, 0, stream>>>(y16, part);
        k_bnfin<<<F / 256, 256, 0, stream>>>(part, gamma[l], beta[l], scale, shift);
        if (l < 2)
            k_bnapply<<<(N_NODES * (F / 8) + 255) / 256, 256, 0, stream>>>(y16, scale, shift, xh);
    }

    // ---- fused BN+pool + MLP head (MFMA fc1/fc2, wave-reduce fc3) ----
    k_pool_bn<<<dim3(4, N_GRAPHS), 256, 0, stream>>>(y16, scale, shift, gstart, hg16);
    k_mlp_mfma<<<16, 256, 0, stream>>>(hg16, fc1h, fc1_b, z1h, nullptr, 0);
    k_mlp_mfma<<<16, 256, 0, stream>>>(z1h, fc2h, fc2_b, nullptr, z2, 1);
    k_fc3<<<(N_GRAPHS * NCLS * 64 + 255) / 256, 256, 0, stream>>>(z2, fc3_w, fc3_b, (float*)d_out);
}